// Round 9
// baseline (1637.817 us; speedup 1.0000x reference)
//
#include <hip/hip_runtime.h>

typedef __attribute__((ext_vector_type(8))) short short8;
typedef __attribute__((ext_vector_type(4))) float float4_t;
typedef __attribute__((ext_vector_type(2))) float float2_t;
typedef __attribute__((ext_vector_type(4))) unsigned int uint4_t;
typedef unsigned short u16;
typedef unsigned int u32;
typedef unsigned long long u64;

// B=256, T=256, IN=128, S=1024
// phases p=0..511: t=p>>1, stage=p&1

__device__ __forceinline__ u16 f2bf(float f) {
  u32 u = __builtin_bit_cast(u32, f);
  u += 0x7fffu + ((u >> 16) & 1u);          // RNE
  return (u16)(u >> 16);
}
__device__ __forceinline__ float bf2f(u16 h) {
  u32 u = ((u32)h) << 16;
  return __builtin_bit_cast(float, u);
}
__device__ __forceinline__ short8 cvt8(float4_t f0, float4_t f1) {
  short8 v;
  v[0]=(short)f2bf(f0[0]); v[1]=(short)f2bf(f0[1]); v[2]=(short)f2bf(f0[2]); v[3]=(short)f2bf(f0[3]);
  v[4]=(short)f2bf(f1[0]); v[5]=(short)f2bf(f1[1]); v[6]=(short)f2bf(f1[2]); v[7]=(short)f2bf(f1[3]);
  return v;
}

// cnt layout (u32 idx): [0..4095] flags (16 groups x 16 WGs; ONE flag per WG at offset 0
//                       of its 16-u32 block), [4096..4351] XCD ids, [4352] publish counter
__global__ __launch_bounds__(256) void init_counter(u32* __restrict__ cnt) {
#pragma unroll
  for (int i = 0; i < 20; ++i) cnt[threadIdx.x + (i << 8)] = 0u;
}

__global__ __launch_bounds__(256) void prep_w(const float* __restrict__ Wr,
                                              const float* __restrict__ Wr2,
                                              u16* __restrict__ W1b,
                                              u16* __restrict__ W2b) {
  const int i = blockIdx.x * 256 + threadIdx.x;   // 0 .. 1048575
  W1b[i] = f2bf(Wr[i]);
  W2b[i] = f2bf(Wr2[i]);
}

// ext GEMM: ebuf[t][b][n] = sum_k x[b][t][k]*Win[n][k] + bin[n], bf16 out.
__global__ __launch_bounds__(256) void ext_gemm(const float* __restrict__ x,
                                                const float* __restrict__ Win,
                                                const float* __restrict__ bin,
                                                u16* __restrict__ ebuf) {
  const int wg = blockIdx.x;
  const int nt = wg & 15, mt = wg >> 4;           // mt 0..1023
  const int tid = threadIdx.x;
  const int wave = tid >> 6, lane = tid & 63, quad = lane >> 4, lm = lane & 15;
  const int m0 = (mt << 6) + (wave << 4);
  const int n0 = nt << 6;

  short8 a[4];
#pragma unroll
  for (int ks = 0; ks < 4; ++ks) {
    const float* p = x + (m0 + lm) * 128 + (ks * 32 + quad * 8);
    a[ks] = cvt8(*(const float4_t*)p, *(const float4_t*)(p + 4));
  }
  short8 bfr[4][4];
#pragma unroll
  for (int nsub = 0; nsub < 4; ++nsub)
#pragma unroll
    for (int ks = 0; ks < 4; ++ks) {
      const float* p = Win + (n0 + (nsub << 4) + lm) * 128 + (ks * 32 + quad * 8);
      bfr[nsub][ks] = cvt8(*(const float4_t*)p, *(const float4_t*)(p + 4));
    }
  float4_t acc[4] = { {0,0,0,0},{0,0,0,0},{0,0,0,0},{0,0,0,0} };
#pragma unroll
  for (int ks = 0; ks < 4; ++ks)
#pragma unroll
    for (int nsub = 0; nsub < 4; ++nsub)
      acc[nsub] = __builtin_amdgcn_mfma_f32_16x16x32_bf16(a[ks], bfr[nsub][ks], acc[nsub], 0, 0, 0);

#pragma unroll
  for (int nsub = 0; nsub < 4; ++nsub) {
    const int n = n0 + (nsub << 4) + lm;
    const float bv = bin[n];
#pragma unroll
    for (int r = 0; r < 4; ++r) {
      const int m = m0 + (quad << 2) + r;
      const int b = m >> 8, t = m & 255;
      ebuf[(((t << 8) | b) << 10) + n] = f2bf(acc[nsub][r] + bv);
    }
  }
}

// 8 x dwordx4 A-fragment load with sc1 (L1-bypass, TCC-executed).
// Fast path: lines are DIRTY in the shared same-XCD L2 -> L2-speed serve, no inv needed.
#define ALOAD8_SC1                                                           \
  asm volatile("global_load_dwordx4 %0, %8, off sc1\n\t"                     \
               "global_load_dwordx4 %1, %8, off offset:64 sc1\n\t"           \
               "global_load_dwordx4 %2, %8, off offset:128 sc1\n\t"          \
               "global_load_dwordx4 %3, %8, off offset:192 sc1\n\t"          \
               "global_load_dwordx4 %4, %8, off offset:256 sc1\n\t"          \
               "global_load_dwordx4 %5, %8, off offset:320 sc1\n\t"          \
               "global_load_dwordx4 %6, %8, off offset:384 sc1\n\t"          \
               "global_load_dwordx4 %7, %8, off offset:448 sc1\n\t"          \
               "s_waitcnt vmcnt(0)"                                          \
               : "=&v"(av[0]), "=&v"(av[1]), "=&v"(av[2]), "=&v"(av[3]),     \
                 "=&v"(av[4]), "=&v"(av[5]), "=&v"(av[6]), "=&v"(av[7])      \
               : "v"(rb) : "memory")

// Persistent recurrence. 256 WGs x 512 thr (8 waves). WG = (mt: 16 batch rows, ns: 64 cols).
// mt = bid & 15: group's 16 WGs share one XCD/L2 (runtime-VERIFIED; agent fallback else).
// v9 delta vs measured r8 (1021us, phase ~4790cy, null result from barrier/flag micro-opts):
// THEORY: the poll storm itself contends the TCC. r8: 64 lanes x 4 waves x 16 WGs ~ 4096
// concurrent agent-atomic loads per XCD on 8 cache lines, continuously. Same-line atomic
// ops serialize in the TCC and inflate every L2 RT in the phase (A-loads, stores, flags).
// FIX: cut poll traffic ~50x:
//  - ONE flag per WG (not 8): posted by the last of the 8 waves, gated by a monotonic LDS
//    counter (each wave ds_add's AFTER its own vmcnt(0) drain; old==8p+7 -> post p+1).
//  - exec-masked poll: only 4 LANES load (4 producer-WG flags per consumer wave).
// Safety identical to r8: union of 4 active waves' polls + mid barrier covers all 16 WGs
// >= p before any epilogue write (WAR); per-wave drain before LDS inc gives RAW; counter
// phases can't interleave (inc sits between barrier p and barrier p+1).
// Phase spins CAPPED (16384 iters): a sync bug terminates with wrong results + counters.
__global__ __launch_bounds__(512, 2) void rnn_persistent(
    const u16* __restrict__ ebuf, u16* __restrict__ buf0, u16* __restrict__ buf1,
    const u16* __restrict__ W1b, const u16* __restrict__ W2b,
    const float* __restrict__ b1, const float* __restrict__ b2,
    float* __restrict__ fbuf, u32* __restrict__ cnt) {
  __shared__ __align__(16) float Pt[2][4][16][68];  // double-buffered k-split partials
  __shared__ int s_fast;
  __shared__ u32 s_arrv;                            // monotonic per-WG arrive counter

  const int tid = threadIdx.x;
  const int wave = tid >> 6, lane = tid & 63, quad = lane >> 4, lm = lane & 15;
  const int mt = blockIdx.x & 15, ns = blockIdx.x >> 4;   // group = same XCD
  const int n0 = ns << 6;
  const int mat = wave >> 2, q = wave & 3;

  // persistent weight fragments: B[k][n], lane: n=lm, k=quad*8+j (within 32-k slice)
  short8 wfrag[4][8];
  {
    const u16* Wm = mat ? W2b : W1b;
#pragma unroll
    for (int nsub = 0; nsub < 4; ++nsub)
#pragma unroll
      for (int ks = 0; ks < 8; ++ks)
        wfrag[nsub][ks] = __builtin_bit_cast(short8,
            *(const uint4*)(Wm + ((n0 + (nsub << 4) + lm) << 10) + (q << 8) + (ks << 5) + (quad << 3)));
  }

  const int me = tid >> 5;               // epilogue row 0..15
  const int nc = (tid & 31) << 1;        // epilogue col base (2 cols)

  // bias hoisted to registers
  const float2_t bv1 = *(const float2_t*)(b1 + n0 + nc);
  const float2_t bv2 = *(const float2_t*)(b2 + n0 + nc);

  if (tid == 0) s_arrv = 0u;

  // ---- one-time XCD co-residency handshake (group -> fast/slow verdict) ----
  {
    const u32 xcc = (u32)__builtin_amdgcn_s_getreg(6164);  // id20(XCC_ID), off0, sz4
    u32* xcb = cnt + 4096;
    if (tid == 0) {
      __hip_atomic_store(xcb + blockIdx.x, xcc + 1u, __ATOMIC_RELAXED, __HIP_MEMORY_SCOPE_AGENT);
      asm volatile("s_waitcnt vmcnt(0)" ::: "memory");
      __hip_atomic_fetch_add(xcb + 256, 1u, __ATOMIC_RELAXED, __HIP_MEMORY_SCOPE_AGENT);
      while (__hip_atomic_load(xcb + 256, __ATOMIC_RELAXED, __HIP_MEMORY_SCOPE_AGENT) < 256u)
        __builtin_amdgcn_s_sleep(2);
    }
    __syncthreads();
    if (wave == 0) {
      bool ok = true;
      if (lane < 16) {
        u32 peer = __hip_atomic_load(xcb + mt + (lane << 4), __ATOMIC_RELAXED,
                                     __HIP_MEMORY_SCOPE_AGENT);
        ok = (peer == xcc + 1u);
      }
      int f = __all((int)ok) ? 1 : 0;
      if (lane == 0) s_fast = f;
    }
    __syncthreads();
  }
  const bool fast = (s_fast != 0);

  u32* gflags = cnt + (mt << 8);            // group's 16 per-WG flags, 16-u32 stride
  u32* myflag = gflags + (ns << 4);         // this WG's flag
  // poll addr for lanes 0-3: flag of producer WG (q*4 + lane)
  u32* pollflag = gflags + (((q << 2) + (lane & 3)) << 4);

  u32 e2v = 0;   // held across a phase for waves issuing with 1-phase lead

  for (int p = 0; p < 512; ++p) {
    const int t = p >> 1, st = p & 1;
    const bool active = (mat == st);

    // e2 prefetch by INACTIVE waves only (latency hidden by their idle wait / next phase)
    {
      const int eidx = (p >> 1) + 1;
      if (!active && eidx < 256)
        e2v = *(const u32*)(ebuf + (((eidx << 8) + (mt << 4) + me) << 10) + n0 + nc);
    }

    const u16* uIn = st ? buf1 : (t == 0 ? ebuf : buf0);

    if (active) {
      if (p) {  // wait for the 4 producer WGs of my k-quarter: 4 LANES poll 4 flags
        int it = 0;
        while (true) {
          u32 v = 0xFFFFFFFFu;
          if (lane < 4)
            v = __hip_atomic_load(pollflag, __ATOMIC_RELAXED, __HIP_MEMORY_SCOPE_AGENT);
          if (__all((int)(v >= (u32)p)) || ++it > 16384) break;
        }
        asm volatile("" ::: "memory");   // keep A-loads below the spin exit
      }
      // A-fragments direct to registers: row lm of this WG's 16-row slice, k-quarter q
      short8 a8[8];
      const u16* rb = uIn + (((mt << 4) + lm) << 10) + (q << 8) + (quad << 3);
      {
        uint4_t av[8];
        ALOAD8_SC1;
#pragma unroll
        for (int ks = 0; ks < 8; ++ks) a8[ks] = __builtin_bit_cast(short8, av[ks]);
      }
      float4_t acc[4] = { {0,0,0,0},{0,0,0,0},{0,0,0,0},{0,0,0,0} };
#pragma unroll
      for (int ks = 0; ks < 8; ++ks) {
#pragma unroll
        for (int nsub = 0; nsub < 4; ++nsub)
          acc[nsub] = __builtin_amdgcn_mfma_f32_16x16x32_bf16(a8[ks], wfrag[nsub][ks], acc[nsub], 0, 0, 0);
      }
#pragma unroll
      for (int nsub = 0; nsub < 4; ++nsub)
#pragma unroll
        for (int r = 0; r < 4; ++r)
          Pt[p & 1][q][(quad << 2) + r][(nsub << 4) + lm] = acc[nsub][r];
    }
    __syncthreads();   // the ONLY barrier per phase: Pt(p) writes -> epilogue reads

    // epilogue: reduce k-split, bias, relu, (+e for stage2), store (512 thr x 2 elems)
    {
      const int par = p & 1;
      const float2_t p0 = *(const float2_t*)&Pt[par][0][me][nc];
      const float2_t p1 = *(const float2_t*)&Pt[par][1][me][nc];
      const float2_t p2 = *(const float2_t*)&Pt[par][2][me][nc];
      const float2_t p3 = *(const float2_t*)&Pt[par][3][me][nc];
      const float2_t bias = st ? bv2 : bv1;
      float2_t s = p0 + p1 + p2 + p3 + bias;
      s[0] = s[0] > 0.f ? s[0] : 0.f;
      s[1] = s[1] > 0.f ? s[1] : 0.f;
      const int gr = (mt << 4) + me;
      if (!st) {
        u32 o = (u32)f2bf(s[0]) | ((u32)f2bf(s[1]) << 16);
        u32* dst = (u32*)(buf1 + (gr << 10) + n0 + nc);
        if (fast) *dst = o;                       // plain: dirty in shared L2, no HBM
        else __hip_atomic_store(dst, o, __ATOMIC_RELAXED, __HIP_MEMORY_SCOPE_AGENT);
      } else if (t < 255) {
        s[0] += bf2f((u16)(e2v & 0xffffu));
        s[1] += bf2f((u16)(e2v >> 16));
        u32 o = (u32)f2bf(s[0]) | ((u32)f2bf(s[1]) << 16);
        u32* dst = (u32*)(buf0 + (gr << 10) + n0 + nc);
        if (fast) *dst = o;
        else __hip_atomic_store(dst, o, __ATOMIC_RELAXED, __HIP_MEMORY_SCOPE_AGENT);
      } else {
        *(float2_t*)(fbuf + (gr << 10) + n0 + nc) = s;  // final state; kernel-end flush
      }
    }

    // arrive: per-wave drain (covers this wave's epilogue stores AND its A-loads/e2),
    // then lane0 ds_add's the monotonic WG counter; the 8th arrival posts the WG flag.
    if (p < 511) {
      asm volatile("s_waitcnt vmcnt(0)" ::: "memory");
      if (lane == 0) {
        u32 old = __hip_atomic_fetch_add(&s_arrv, 1u, __ATOMIC_RELAXED,
                                         __HIP_MEMORY_SCOPE_WORKGROUP);
        if (old == (((u32)p) << 3) + 7u) {
          if (fast) *myflag = (u32)(p + 1);
          else __hip_atomic_store(myflag, (u32)(p + 1), __ATOMIC_RELAXED,
                                  __HIP_MEMORY_SCOPE_AGENT);
        }
      }
    }
  }
}

__global__ __launch_bounds__(256) void bcast(const float* __restrict__ fbuf,
                                             float* __restrict__ out) {
  const int idx4 = blockIdx.x * 256 + threadIdx.x;   // 0..16777215 float4s
  const int b = idx4 >> 16;
  const int s4 = idx4 & 255;
  const float4_t v = *(const float4_t*)(fbuf + (b << 10) + (s4 << 2));
  *(float4_t*)(out + ((size_t)idx4 << 2)) = v;
}

extern "C" void kernel_launch(void* const* d_in, const int* in_sizes, int n_in,
                              void* d_out, int out_size, void* d_ws, size_t ws_size,
                              hipStream_t stream) {
  const float* x     = (const float*)d_in[0];
  const float* Win   = (const float*)d_in[1];
  const float* bin   = (const float*)d_in[2];
  const float* Wrec  = (const float*)d_in[3];
  const float* brec  = (const float*)d_in[4];
  const float* Wrec2 = (const float*)d_in[5];
  const float* brec2 = (const float*)d_in[6];
  float* out = (float*)d_out;

  char* ws = (char*)d_ws;
  u16* W1b  = (u16*)(ws);                               // 2 MB
  u16* W2b  = (u16*)(ws + (2u << 20));                  // 2 MB
  u16* buf0 = (u16*)(ws + (4u << 20));                  // 512 KB
  u16* buf1 = (u16*)(ws + (4u << 20) + (512u << 10));   // 512 KB
  float* fbuf = (float*)(ws + (5u << 20));              // 1 MB
  u32* cnt  = (u32*)(ws + (6u << 20));                  // 20 KB (flags + XCD ids + counter)
  u16* ebuf = (u16*)d_out;  // 128 MB scratch inside out (268 MB); dead before bcast

  init_counter<<<1, 256, 0, stream>>>(cnt);
  prep_w<<<4096, 256, 0, stream>>>(Wrec, Wrec2, W1b, W2b);
  ext_gemm<<<16384, 256, 0, stream>>>(x, Win, bin, ebuf);

  void* args[] = { (void*)&ebuf, (void*)&buf0, (void*)&buf1, (void*)&W1b, (void*)&W2b,
                   (void*)&brec, (void*)&brec2, (void*)&fbuf, (void*)&cnt };
  (void)hipLaunchCooperativeKernel(reinterpret_cast<void*>(rnn_persistent),
                                   dim3(256), dim3(512), args, 0, stream);

  bcast<<<65536, 256, 0, stream>>>(fbuf, out);
}

// Round 10
// 1413.840 us; speedup vs baseline: 1.1584x; 1.1584x over previous
//
#include <hip/hip_runtime.h>

typedef __attribute__((ext_vector_type(8))) short short8;
typedef __attribute__((ext_vector_type(4))) float float4_t;
typedef __attribute__((ext_vector_type(2))) float float2_t;
typedef __attribute__((ext_vector_type(4))) unsigned int uint4_t;
typedef unsigned short u16;
typedef unsigned int u32;
typedef unsigned long long u64;

// B=256, T=256, IN=128, S=1024
// phases p=0..511: t=p>>1, stage=p&1

__device__ __forceinline__ u16 f2bf(float f) {
  u32 u = __builtin_bit_cast(u32, f);
  u += 0x7fffu + ((u >> 16) & 1u);          // RNE
  return (u16)(u >> 16);
}
__device__ __forceinline__ float bf2f(u16 h) {
  u32 u = ((u32)h) << 16;
  return __builtin_bit_cast(float, u);
}
__device__ __forceinline__ short8 cvt8(float4_t f0, float4_t f1) {
  short8 v;
  v[0]=(short)f2bf(f0[0]); v[1]=(short)f2bf(f0[1]); v[2]=(short)f2bf(f0[2]); v[3]=(short)f2bf(f0[3]);
  v[4]=(short)f2bf(f1[0]); v[5]=(short)f2bf(f1[1]); v[6]=(short)f2bf(f1[2]); v[7]=(short)f2bf(f1[3]);
  return v;
}

// cnt layout (u32 idx): [0..4095] flags (16 groups x 16 WGs x 8 waves; WG block = 16 u32,
//                       wave flag at offset `wave`), [4096..4351] XCD ids, [4352] counter
__global__ __launch_bounds__(256) void init_counter(u32* __restrict__ cnt) {
#pragma unroll
  for (int i = 0; i < 20; ++i) cnt[threadIdx.x + (i << 8)] = 0u;
}

__global__ __launch_bounds__(256) void prep_w(const float* __restrict__ Wr,
                                              const float* __restrict__ Wr2,
                                              u16* __restrict__ W1b,
                                              u16* __restrict__ W2b) {
  const int i = blockIdx.x * 256 + threadIdx.x;   // 0 .. 1048575
  W1b[i] = f2bf(Wr[i]);
  W2b[i] = f2bf(Wr2[i]);
}

// ext GEMM v2: ebuf[t][b][n] = sum_k x[b][t][k]*Win[n][k] + bin[n], bf16 out.
// BM=64, BN=128, B staged once in LDS (bf16, padded 16B-aligned rows).
// vs v1 (64x64, B re-loaded per WG from global): A amp 16->8 (512->256MB), B now
// read once per WG into LDS instead of 64KB of VGPR-loads per thread-block.
__global__ __launch_bounds__(256) void ext_gemm(const float* __restrict__ x,
                                                const float* __restrict__ Win,
                                                const float* __restrict__ bin,
                                                u16* __restrict__ ebuf) {
  __shared__ __align__(16) u16 sB[128 * 136];     // [col][k] bf16, row stride 136 (272B)
  const int wg = blockIdx.x;                      // 0..8191
  const int nt = wg & 7, mt = wg >> 3;            // nt 0..7, mt 0..1023
  const int tid = threadIdx.x;
  const int wave = tid >> 6, lane = tid & 63, quad = lane >> 4, lm = lane & 15;
  const int m0 = (mt << 6) + (wave << 4);
  const int n0 = nt << 7;

  // stage Win[n0 + col][0..127] -> sB[col][k]; thread: col=tid&127, half=tid>>7 (64 f32)
  {
    const int col = tid & 127, half = tid >> 7;
    const float* src = Win + ((n0 + col) << 7) + (half << 6);
    u16* dst = sB + col * 136 + (half << 6);
#pragma unroll
    for (int kk = 0; kk < 8; ++kk) {
      const float4_t f0 = *(const float4_t*)(src + (kk << 3));
      const float4_t f1 = *(const float4_t*)(src + (kk << 3) + 4);
      *(short8*)(dst + (kk << 3)) = cvt8(f0, f1);
    }
  }

  // A fragments (rows m0+lm, k quad*8 within 32-k slices), f32 -> bf16
  short8 a[4];
#pragma unroll
  for (int ks = 0; ks < 4; ++ks) {
    const float* p = x + (m0 + lm) * 128 + (ks * 32 + quad * 8);
    a[ks] = cvt8(*(const float4_t*)p, *(const float4_t*)(p + 4));
  }
  __syncthreads();

  float4_t acc[8] = { {0,0,0,0},{0,0,0,0},{0,0,0,0},{0,0,0,0},
                      {0,0,0,0},{0,0,0,0},{0,0,0,0},{0,0,0,0} };
#pragma unroll
  for (int ks = 0; ks < 4; ++ks) {
#pragma unroll
    for (int ns = 0; ns < 8; ++ns) {
      const short8 bf = *(const short8*)&sB[((ns << 4) + lm) * 136 + (ks << 5) + (quad << 3)];
      acc[ns] = __builtin_amdgcn_mfma_f32_16x16x32_bf16(a[ks], bf, acc[ns], 0, 0, 0);
    }
  }

#pragma unroll
  for (int ns = 0; ns < 8; ++ns) {
    const int n = n0 + (ns << 4) + lm;
    const float bv = bin[n];
#pragma unroll
    for (int r = 0; r < 4; ++r) {
      const int m = m0 + (quad << 2) + r;
      const int b = m >> 8, t = m & 255;
      ebuf[(((t << 8) | b) << 10) + n] = f2bf(acc[ns][r] + bv);
    }
  }
}

// Persistent recurrence. 256 WGs x 512 thr (8 waves). WG = (mt: 16 batch rows, ns: 64 cols).
// mt = bid & 15: group's 16 WGs share one XCD/L2 (runtime-VERIFIED; agent fallback else).
// Structure identical to the measured r8 kernel (1021us) EXCEPT the A-load/MFMA overlap:
// issue all 8 sc1 dwordx4, wait vmcnt(4), run ks0-3 MFMAs while ks4-7 land, then vmcnt(0)
// + sched_barrier (rule #18: register-only MFMA can hoist past inline-asm waitcnt).
// Saves ~300-500cy of the serial {load-all -> mfma-all} chain per phase.
// Phase spins CAPPED (16384 iters): a sync bug terminates with wrong results + counters.
__global__ __launch_bounds__(512, 2) void rnn_persistent(
    const u16* __restrict__ ebuf, u16* __restrict__ buf0, u16* __restrict__ buf1,
    const u16* __restrict__ W1b, const u16* __restrict__ W2b,
    const float* __restrict__ b1, const float* __restrict__ b2,
    float* __restrict__ fbuf, u32* __restrict__ cnt) {
  __shared__ __align__(16) float Pt[2][4][16][68];  // double-buffered k-split partials
  __shared__ int s_fast;

  const int tid = threadIdx.x;
  const int wave = tid >> 6, lane = tid & 63, quad = lane >> 4, lm = lane & 15;
  const int mt = blockIdx.x & 15, ns = blockIdx.x >> 4;   // group = same XCD
  const int n0 = ns << 6;
  const int mat = wave >> 2, q = wave & 3;

  // persistent weight fragments: B[k][n], lane: n=lm, k=quad*8+j (within 32-k slice)
  short8 wfrag[4][8];
  {
    const u16* Wm = mat ? W2b : W1b;
#pragma unroll
    for (int nsub = 0; nsub < 4; ++nsub)
#pragma unroll
      for (int ks = 0; ks < 8; ++ks)
        wfrag[nsub][ks] = __builtin_bit_cast(short8,
            *(const uint4*)(Wm + ((n0 + (nsub << 4) + lm) << 10) + (q << 8) + (ks << 5) + (quad << 3)));
  }

  const int me = tid >> 5;               // epilogue row 0..15
  const int nc = (tid & 31) << 1;        // epilogue col base (2 cols)

  // bias hoisted to registers
  const float2_t bv1 = *(const float2_t*)(b1 + n0 + nc);
  const float2_t bv2 = *(const float2_t*)(b2 + n0 + nc);

  // ---- one-time XCD co-residency handshake (group -> fast/slow verdict) ----
  {
    const u32 xcc = (u32)__builtin_amdgcn_s_getreg(6164);  // id20(XCC_ID), off0, sz4
    u32* xcb = cnt + 4096;
    if (tid == 0) {
      __hip_atomic_store(xcb + blockIdx.x, xcc + 1u, __ATOMIC_RELAXED, __HIP_MEMORY_SCOPE_AGENT);
      asm volatile("s_waitcnt vmcnt(0)" ::: "memory");
      __hip_atomic_fetch_add(xcb + 256, 1u, __ATOMIC_RELAXED, __HIP_MEMORY_SCOPE_AGENT);
      while (__hip_atomic_load(xcb + 256, __ATOMIC_RELAXED, __HIP_MEMORY_SCOPE_AGENT) < 256u)
        __builtin_amdgcn_s_sleep(2);
    }
    __syncthreads();
    if (wave == 0) {
      bool ok = true;
      if (lane < 16) {
        u32 peer = __hip_atomic_load(xcb + mt + (lane << 4), __ATOMIC_RELAXED,
                                     __HIP_MEMORY_SCOPE_AGENT);
        ok = (peer == xcc + 1u);
      }
      int f = __all((int)ok) ? 1 : 0;
      if (lane == 0) s_fast = f;
    }
    __syncthreads();
  }
  const bool fast = (s_fast != 0);

  u32* gflags = cnt + (mt << 8);                    // group's flags, 16-u32 stride per WG
  u32* myflag = gflags + (ns << 4) + wave;          // this wave's flag
  // poll: 32 flags = 4 producer WGs (q*4..q*4+3) x 8 waves, one per lane (lanes 32-63 dup)
  const u32* pollflag = gflags + (((q << 2) + ((lane >> 3) & 3)) << 4) + (lane & 7);

  u32 e2v = 0;   // held across a phase for waves issuing with 1-phase lead

  for (int p = 0; p < 512; ++p) {
    const int t = p >> 1, st = p & 1;
    const bool active = (mat == st);

    // e2 prefetch by INACTIVE waves only (latency hidden by their idle wait / next phase)
    {
      const int eidx = (p >> 1) + 1;
      if (!active && eidx < 256)
        e2v = *(const u32*)(ebuf + (((eidx << 8) + (mt << 4) + me) << 10) + n0 + nc);
    }

    const u16* uIn = st ? buf1 : (t == 0 ? ebuf : buf0);

    if (active) {
      if (p) {  // wait for the 4 WGs (x8 waves) producing my k-quarter to finish p-1
        int it = 0;
        while (true) {
          u32 v = __hip_atomic_load(pollflag, __ATOMIC_RELAXED, __HIP_MEMORY_SCOPE_AGENT);
          if (__all((int)(v >= (u32)p)) || ++it > 16384) break;
        }
        asm volatile("" ::: "memory");   // keep A-loads below the spin exit
      }
      // A-fragments direct to registers: row lm of this WG's 16-row slice, k-quarter q
      const u16* rb = uIn + (((mt << 4) + lm) << 10) + (q << 8) + (quad << 3);
      float4_t acc[4] = { {0,0,0,0},{0,0,0,0},{0,0,0,0},{0,0,0,0} };
      if (fast) {
        uint4_t av[8];
        // issue all 8 sc1 loads; wait only the first 4 -> overlap ks4-7 landing with MFMA
        asm volatile("global_load_dwordx4 %0, %8, off sc1\n\t"
                     "global_load_dwordx4 %1, %8, off offset:64 sc1\n\t"
                     "global_load_dwordx4 %2, %8, off offset:128 sc1\n\t"
                     "global_load_dwordx4 %3, %8, off offset:192 sc1\n\t"
                     "global_load_dwordx4 %4, %8, off offset:256 sc1\n\t"
                     "global_load_dwordx4 %5, %8, off offset:320 sc1\n\t"
                     "global_load_dwordx4 %6, %8, off offset:384 sc1\n\t"
                     "global_load_dwordx4 %7, %8, off offset:448 sc1\n\t"
                     "s_waitcnt vmcnt(4)"
                     : "=&v"(av[0]), "=&v"(av[1]), "=&v"(av[2]), "=&v"(av[3]),
                       "=&v"(av[4]), "=&v"(av[5]), "=&v"(av[6]), "=&v"(av[7])
                     : "v"(rb) : "memory");
        __builtin_amdgcn_sched_barrier(0);
#pragma unroll
        for (int ks = 0; ks < 4; ++ks) {
          const short8 a = __builtin_bit_cast(short8, av[ks]);
#pragma unroll
          for (int nsub = 0; nsub < 4; ++nsub)
            acc[nsub] = __builtin_amdgcn_mfma_f32_16x16x32_bf16(a, wfrag[nsub][ks], acc[nsub], 0, 0, 0);
        }
        asm volatile("s_waitcnt vmcnt(0)" ::: "memory");
        __builtin_amdgcn_sched_barrier(0);
#pragma unroll
        for (int ks = 4; ks < 8; ++ks) {
          const short8 a = __builtin_bit_cast(short8, av[ks]);
#pragma unroll
          for (int nsub = 0; nsub < 4; ++nsub)
            acc[nsub] = __builtin_amdgcn_mfma_f32_16x16x32_bf16(a, wfrag[nsub][ks], acc[nsub], 0, 0, 0);
        }
      } else {
#pragma unroll
        for (int ks = 0; ks < 8; ++ks) {
          const u64* pk = (const u64*)(rb + (ks << 5));
          u64 w0 = __hip_atomic_load(pk, __ATOMIC_RELAXED, __HIP_MEMORY_SCOPE_AGENT);
          u64 w1 = __hip_atomic_load(pk + 1, __ATOMIC_RELAXED, __HIP_MEMORY_SCOPE_AGENT);
          uint4_t wv; wv[0] = (u32)w0; wv[1] = (u32)(w0 >> 32); wv[2] = (u32)w1; wv[3] = (u32)(w1 >> 32);
          const short8 a = __builtin_bit_cast(short8, wv);
#pragma unroll
          for (int nsub = 0; nsub < 4; ++nsub)
            acc[nsub] = __builtin_amdgcn_mfma_f32_16x16x32_bf16(a, wfrag[nsub][ks], acc[nsub], 0, 0, 0);
        }
      }
#pragma unroll
      for (int nsub = 0; nsub < 4; ++nsub)
#pragma unroll
        for (int r = 0; r < 4; ++r)
          Pt[p & 1][q][(quad << 2) + r][(nsub << 4) + lm] = acc[nsub][r];
    }
    __syncthreads();   // the ONLY barrier per phase: Pt(p) writes -> epilogue reads

    // epilogue: reduce k-split, bias, relu, (+e for stage2), store (512 thr x 2 elems)
    {
      const int par = p & 1;
      const float2_t p0 = *(const float2_t*)&Pt[par][0][me][nc];
      const float2_t p1 = *(const float2_t*)&Pt[par][1][me][nc];
      const float2_t p2 = *(const float2_t*)&Pt[par][2][me][nc];
      const float2_t p3 = *(const float2_t*)&Pt[par][3][me][nc];
      const float2_t bias = st ? bv2 : bv1;
      float2_t s = p0 + p1 + p2 + p3 + bias;
      s[0] = s[0] > 0.f ? s[0] : 0.f;
      s[1] = s[1] > 0.f ? s[1] : 0.f;
      const int gr = (mt << 4) + me;
      if (!st) {
        u32 o = (u32)f2bf(s[0]) | ((u32)f2bf(s[1]) << 16);
        u32* dst = (u32*)(buf1 + (gr << 10) + n0 + nc);
        if (fast) *dst = o;                       // plain: dirty in shared L2, no HBM
        else __hip_atomic_store(dst, o, __ATOMIC_RELAXED, __HIP_MEMORY_SCOPE_AGENT);
      } else if (t < 255) {
        s[0] += bf2f((u16)(e2v & 0xffffu));
        s[1] += bf2f((u16)(e2v >> 16));
        u32 o = (u32)f2bf(s[0]) | ((u32)f2bf(s[1]) << 16);
        u32* dst = (u32*)(buf0 + (gr << 10) + n0 + nc);
        if (fast) *dst = o;
        else __hip_atomic_store(dst, o, __ATOMIC_RELAXED, __HIP_MEMORY_SCOPE_AGENT);
      } else {
        *(float2_t*)(fbuf + (gr << 10) + n0 + nc) = s;  // final state; kernel-end flush
      }
    }

    // arrive: PER-WAVE drain (covers this wave's epilogue stores AND its A-loads),
    // then lane0 posts this wave's flag. No second barrier.
    if (p < 511) {
      asm volatile("s_waitcnt vmcnt(0)" ::: "memory");
      if (lane == 0) {
        if (fast) *myflag = (u32)(p + 1);
        else __hip_atomic_store(myflag, (u32)(p + 1), __ATOMIC_RELAXED, __HIP_MEMORY_SCOPE_AGENT);
      }
    }
  }
}

__global__ __launch_bounds__(256) void bcast(const float* __restrict__ fbuf,
                                             float* __restrict__ out) {
  const int idx4 = blockIdx.x * 256 + threadIdx.x;   // 0..16777215 float4s
  const int b = idx4 >> 16;
  const int s4 = idx4 & 255;
  const float4_t v = *(const float4_t*)(fbuf + (b << 10) + (s4 << 2));
  *(float4_t*)(out + ((size_t)idx4 << 2)) = v;
}

extern "C" void kernel_launch(void* const* d_in, const int* in_sizes, int n_in,
                              void* d_out, int out_size, void* d_ws, size_t ws_size,
                              hipStream_t stream) {
  const float* x     = (const float*)d_in[0];
  const float* Win   = (const float*)d_in[1];
  const float* bin   = (const float*)d_in[2];
  const float* Wrec  = (const float*)d_in[3];
  const float* brec  = (const float*)d_in[4];
  const float* Wrec2 = (const float*)d_in[5];
  const float* brec2 = (const float*)d_in[6];
  float* out = (float*)d_out;

  char* ws = (char*)d_ws;
  u16* W1b  = (u16*)(ws);                               // 2 MB
  u16* W2b  = (u16*)(ws + (2u << 20));                  // 2 MB
  u16* buf0 = (u16*)(ws + (4u << 20));                  // 512 KB
  u16* buf1 = (u16*)(ws + (4u << 20) + (512u << 10));   // 512 KB
  float* fbuf = (float*)(ws + (5u << 20));              // 1 MB
  u32* cnt  = (u32*)(ws + (6u << 20));                  // 20 KB (flags + XCD ids + counter)
  u16* ebuf = (u16*)d_out;  // 128 MB scratch inside out (268 MB); dead before bcast

  init_counter<<<1, 256, 0, stream>>>(cnt);
  prep_w<<<4096, 256, 0, stream>>>(Wrec, Wrec2, W1b, W2b);
  ext_gemm<<<8192, 256, 0, stream>>>(x, Win, bin, ebuf);

  void* args[] = { (void*)&ebuf, (void*)&buf0, (void*)&buf1, (void*)&W1b, (void*)&W2b,
                   (void*)&brec, (void*)&brec2, (void*)&fbuf, (void*)&cnt };
  (void)hipLaunchCooperativeKernel(reinterpret_cast<void*>(rnn_persistent),
                                   dim3(256), dim3(512), args, 0, stream);

  bcast<<<65536, 256, 0, stream>>>(fbuf, out);
}